// Round 15
// baseline (989.083 us; speedup 1.0000x reference)
//
#include <hip/hip_runtime.h>
#include <hip/hip_bf16.h>

// Problem constants
#define BATCH   64
#define SEQ     512
#define IN0     512
#define HID     128
#define G3      384   // 3*HID
#define NLAY    5
#define CHUNK   8     // handoff granularity (one release/acquire per CHUNK steps)

typedef _Float16 f16x8 __attribute__((ext_vector_type(8)));
typedef float    f32x4 __attribute__((ext_vector_type(4)));

static __device__ __forceinline__ float sigf(float x) {
    return __builtin_amdgcn_rcpf(1.f + __expf(-x));
}
static __device__ __forceinline__ float tanh_fast(float x) {
    const float e = __expf(-2.f * fabsf(x));
    return copysignf((1.f - e) * __builtin_amdgcn_rcpf(1.f + e), x);
}

// ---------------------------------------------------------------------------
// gru_fused: ONE kernel, two roles.
//   blocks 0..19      : gru_pipeline (R14 verbatim) — 5 layers x 4 groups
//   blocks 20..1555   : gemm tiles gx0 = x @ w_ih0^T + b_ih0 (f16 MFMA),
//                       M=128 x N=64 tiles, t-chunk-major dispatch order.
// Producer->consumer gx0 handoff (no wbl2/inv):
//   gemm epilogue stores gx0 via RELAXED AGENT atomic f32 (write-through,
//   coherent at scope per the memory model), __syncthreads (vmcnt0 -> stores
//   complete at LLC), then one device-scope atomicAdd on gxcnt[group][tc]
//   (96 tiles per counter). Layer-0 spins on gxcnt once per 128 steps;
//   its gx reads are first-touch -> fetch fresh LLC copy (now LLC-resident).
// Deadlock-free: gemm blocks never wait; pipeline blocks are blockIdx 0-19.
// ---------------------------------------------------------------------------
__global__ __launch_bounds__(512, 2) void gru_fused(
    const float* __restrict__ x,          // [64][512][512]
    const float* __restrict__ w_ih0,      // [384][512]
    const float* __restrict__ w_ih_rest,  // [4][384][128]
    const float* __restrict__ w_hh,       // [5][384][128]
    const float* __restrict__ b_ih,       // [5][384]
    const float* __restrict__ b_hh,       // [5][384]
    float* __restrict__ gx0,              // [64][512][384] (workspace)
    _Float16* __restrict__ hmid,          // [4][4][512][16][128]
    float* __restrict__ hlast,            // [64][128]
    int* __restrict__ flags,              // [16] layer handoff
    int* __restrict__ gxcnt)              // [16] = [group][tchunk] gemm progress
{
    const int tid  = threadIdx.x;
    const int lane = tid & 63;
    const int n16  = lane & 15;
    const int quad = lane >> 4;
    const int wv   = tid >> 6;

    // ======================= GEMM ROLE =======================
    if (blockIdx.x >= 20) {
        __shared__ __align__(16) _Float16 As[128][40];
        __shared__ __align__(16) _Float16 Bs[64][40];

        const int gid   = blockIdx.x - 20;       // 0..1535
        const int q     = gid / 6;               // 0..255
        const int ntile = gid % 6;
        const int tc    = q >> 6;                // t-chunk 0..3 (outermost!)
        const int b     = q & 63;                // batch
        const int mt    = b * 4 + tc;            // m-tile index
        const int row0  = mt * 128;
        const int col0  = ntile * 64;
        const int ar    = tid >> 2;              // A staging row 0..127
        const int kc    = (tid & 3) * 8;

        f32x4 acc[4];
        #pragma unroll
        for (int nt = 0; nt < 4; nt++) acc[nt] = (f32x4){0.f, 0.f, 0.f, 0.f};

        for (int k0 = 0; k0 < IN0; k0 += 32) {
            {
                const float* Ap = x + (size_t)(row0 + ar) * IN0 + k0 + kc;
                float4 a0 = *(const float4*)(Ap);
                float4 a1 = *(const float4*)(Ap + 4);
                f16x8 v;
                v[0] = (_Float16)a0.x; v[1] = (_Float16)a0.y; v[2] = (_Float16)a0.z; v[3] = (_Float16)a0.w;
                v[4] = (_Float16)a1.x; v[5] = (_Float16)a1.y; v[6] = (_Float16)a1.z; v[7] = (_Float16)a1.w;
                *(f16x8*)&As[ar][kc] = v;
            }
            if (tid < 256) {
                const float* Wp = w_ih0 + (size_t)(col0 + (tid >> 2)) * IN0 + k0 + kc;
                float4 b0 = *(const float4*)(Wp);
                float4 b1 = *(const float4*)(Wp + 4);
                f16x8 v;
                v[0] = (_Float16)b0.x; v[1] = (_Float16)b0.y; v[2] = (_Float16)b0.z; v[3] = (_Float16)b0.w;
                v[4] = (_Float16)b1.x; v[5] = (_Float16)b1.y; v[6] = (_Float16)b1.z; v[7] = (_Float16)b1.w;
                *(f16x8*)&Bs[tid >> 2][kc] = v;
            }
            __syncthreads();

            const f16x8 af = *(const f16x8*)&As[wv * 16 + n16][quad * 8];
            #pragma unroll
            for (int nt = 0; nt < 4; nt++) {
                const f16x8 bfr = *(const f16x8*)&Bs[nt * 16 + n16][quad * 8];
                acc[nt] = __builtin_amdgcn_mfma_f32_16x16x32_f16(af, bfr, acc[nt], 0, 0, 0);
            }
            __syncthreads();
        }

        // epilogue: bias + write-through stores (visible at LLC on vmcnt drain)
        #pragma unroll
        for (int nt = 0; nt < 4; nt++) {
            const int col = col0 + nt * 16 + n16;
            const float bb = b_ih[col];   // layer-0 bias folded into gx0
            #pragma unroll
            for (int r4 = 0; r4 < 4; r4++) {
                const int row = row0 + wv * 16 + quad * 4 + r4;
                __hip_atomic_store(&gx0[(size_t)row * G3 + col], acc[nt][r4] + bb,
                                   __ATOMIC_RELAXED, __HIP_MEMORY_SCOPE_AGENT);
            }
        }
        __syncthreads();   // all waves' stores complete at LLC
        if (tid == 0) atomicAdd(&gxcnt[(mt >> 6) * 4 + (mt & 3)], 1);
        return;
    }

    // ======================= PIPELINE ROLE (R14 verbatim + gxcnt spin) ======
    const int l    = blockIdx.x >> 2;
    const int g    = blockIdx.x & 3;
    const int bm0  = g * 16;
    const int j    = wv * 16 + n16;       // hidden index this lane finalizes

    __shared__ __align__(16) _Float16 hA[2][16][136];
    __shared__ int barcnt;

    // ---- B-frags for w_hh ----
    f16x8 bf[3][4];
    {
        const float* wb = w_hh + (size_t)l * G3 * HID;
        #pragma unroll
        for (int tau = 0; tau < 3; tau++)
            #pragma unroll
            for (int kc = 0; kc < 4; kc++) {
                const float* wp = wb + (size_t)(tau * 128 + j) * HID + kc * 32 + quad * 8;
                f16x8 v;
                #pragma unroll
                for (int i = 0; i < 8; i++) v[i] = (_Float16)wp[i];
                bf[tau][kc] = v;
            }
    }
    // ---- B-frags for w_ih (layers >= 1) ----
    f16x8 bi[3][4];
    if (l > 0) {
        const float* wb = w_ih_rest + (size_t)(l - 1) * G3 * HID;
        #pragma unroll
        for (int tau = 0; tau < 3; tau++)
            #pragma unroll
            for (int kc = 0; kc < 4; kc++) {
                const float* wp = wb + (size_t)(tau * 128 + j) * HID + kc * 32 + quad * 8;
                f16x8 v;
                #pragma unroll
                for (int i = 0; i < 8; i++) v[i] = (_Float16)wp[i];
                bi[tau][kc] = v;
            }
    }
    // folded gate biases (gx0 already contains b_ih for layer 0)
    const float bcr = b_hh[l * G3 + j]       + ((l > 0) ? b_ih[l * G3 + j]       : 0.f);
    const float bcz = b_hh[l * G3 + j + 128] + ((l > 0) ? b_ih[l * G3 + j + 128] : 0.f);
    const float bcn = b_hh[l * G3 + j + 256];
    const float bxn = (l > 0) ? b_ih[l * G3 + j + 256] : 0.f;

    // ---- zero h state ----
    for (int i = tid; i < 2 * 16 * 136; i += 512) ((_Float16*)hA)[i] = (_Float16)0.f;
    float vhp[4] = {0.f, 0.f, 0.f, 0.f};
    if (tid == 0) barcnt = 0;
    __syncthreads();   // hA zero + barcnt visible

    // ---- layer-0 gx pointers; preload t=0 AFTER gx t-chunk 0 is ready ----
    const float* pR[4];
    float xr[4], xz[4], xn[4];
    int tcdone = 0;
    if (l == 0) {
        int v = __hip_atomic_load(&gxcnt[g * 4], __ATOMIC_RELAXED, __HIP_MEMORY_SCOPE_AGENT);
        while (v < 96) {
            __builtin_amdgcn_s_sleep(8);
            v = __hip_atomic_load(&gxcnt[g * 4], __ATOMIC_RELAXED, __HIP_MEMORY_SCOPE_AGENT);
        }
        __asm__ volatile("" ::: "memory");
        tcdone = 1;
        #pragma unroll
        for (int r = 0; r < 4; r++) {
            pR[r] = gx0 + (size_t)(bm0 + quad * 4 + r) * SEQ * G3 + j;
            xr[r] = pR[r][0]; xz[r] = pR[r][128]; xn[r] = pR[r][256];
            pR[r] += G3;
        }
    }

    const _Float16* hprev = (l > 0) ? hmid + (size_t)((l - 1) * 4 + g) * SEQ * 2048 : (const _Float16*)nullptr;
    _Float16*       hpub  = (l < 4) ? hmid + (size_t)(l * 4 + g) * SEQ * 2048 : (_Float16*)nullptr;
    int*       dstflag = (l < 4) ? &flags[l * 4 + g] : (int*)nullptr;
    const int* srcflag = (l > 0) ? &flags[(l - 1) * 4 + g] : (const int*)nullptr;

    _Float16* hw = (l < 4) ? hpub + quad * 4 * 128 + j : (_Float16*)nullptr;  // walks by 2048/step

    f16x8 ap[4];                             // h_prev(t) A-frags
    const int hoff = n16 * 128 + quad * 8;   // A-frag base (m=n16, k=quad*8)

    volatile int* bc = &barcnt;
    int btarget = 0;

    for (int c = 0; c < SEQ / CHUNK; c++) {
        const int t0 = c * CHUNK;

        if (l > 0) {
            // once-per-chunk: relaxed spin, then ONE acquire load (buffer_inv)
            const int need = t0 + CHUNK;
            int v = __hip_atomic_load(srcflag, __ATOMIC_RELAXED, __HIP_MEMORY_SCOPE_AGENT);
            while (v < need) {
                __builtin_amdgcn_s_sleep(2);
                v = __hip_atomic_load(srcflag, __ATOMIC_RELAXED, __HIP_MEMORY_SCOPE_AGENT);
            }
            (void)__hip_atomic_load(srcflag, __ATOMIC_ACQUIRE, __HIP_MEMORY_SCOPE_AGENT);
            __asm__ volatile("" ::: "memory");
            const _Float16* hp = hprev + (size_t)t0 * 2048 + hoff;
            #pragma unroll
            for (int kc = 0; kc < 4; kc++) ap[kc] = *(const f16x8*)(hp + kc * 32);
        } else {
            // layer-0: ensure gx ready through t0+CHUNK (prefetch horizon)
            const int tneed = (t0 + CHUNK < SEQ) ? (t0 + CHUNK) : (SEQ - 1);
            const int tc = tneed >> 7;
            if (tc >= tcdone) {
                int v = __hip_atomic_load(&gxcnt[g * 4 + tc], __ATOMIC_RELAXED, __HIP_MEMORY_SCOPE_AGENT);
                while (v < 96) {
                    __builtin_amdgcn_s_sleep(2);
                    v = __hip_atomic_load(&gxcnt[g * 4 + tc], __ATOMIC_RELAXED, __HIP_MEMORY_SCOPE_AGENT);
                }
                __asm__ volatile("" ::: "memory");
                tcdone = tc + 1;
            }
        }

        #pragma unroll
        for (int i = 0; i < CHUNK; i++) {
            const int t = t0 + i;

            // ---- LDS flag barrier: no vmcnt drain (stores stay in flight) ----
            __asm__ volatile("" ::: "memory");
            if (lane == 0) atomicAdd(&barcnt, 1);
            btarget += 8;
            while (*bc < btarget) { __builtin_amdgcn_s_sleep(1); }
            __asm__ volatile("" ::: "memory");

            const int buf = t & 1;
            // issue af LDS reads first (latency overlapped by ih MFMAs below)
            f16x8 af[4];
            #pragma unroll
            for (int kc = 0; kc < 4; kc++)
                af[kc] = *(const f16x8*)&hA[buf][n16][kc * 32 + quad * 8];

            // ih MFMAs (register inputs, no LDS dependency) — issue first
            f32x4 ai0 = {0.f,0.f,0.f,0.f}, ai1 = ai0, ai2 = ai0;
            if (l > 0) {
                #pragma unroll
                for (int kc = 0; kc < 4; kc++) {
                    ai0 = __builtin_amdgcn_mfma_f32_16x16x32_f16(ap[kc], bi[0][kc], ai0, 0, 0, 0);
                    ai1 = __builtin_amdgcn_mfma_f32_16x16x32_f16(ap[kc], bi[1][kc], ai1, 0, 0, 0);
                    ai2 = __builtin_amdgcn_mfma_f32_16x16x32_f16(ap[kc], bi[2][kc], ai2, 0, 0, 0);
                }
            }
            // layer-0: issue gx(t+1) prefetch
            float nr[4], nz[4], nn[4];
            if (l == 0) {
                #pragma unroll
                for (int r = 0; r < 4; r++) {
                    nr[r] = pR[r][0]; nz[r] = pR[r][128]; nn[r] = pR[r][256];
                }
                if (t + 1 < SEQ) {
                    #pragma unroll
                    for (int r = 0; r < 4; r++) pR[r] += G3;
                }
            }

            // hh MFMAs
            f32x4 ah0 = {0.f,0.f,0.f,0.f}, ah1 = ah0, ah2 = ah0;
            #pragma unroll
            for (int kc = 0; kc < 4; kc++) {
                ah0 = __builtin_amdgcn_mfma_f32_16x16x32_f16(af[kc], bf[0][kc], ah0, 0, 0, 0);
                ah1 = __builtin_amdgcn_mfma_f32_16x16x32_f16(af[kc], bf[1][kc], ah1, 0, 0, 0);
                ah2 = __builtin_amdgcn_mfma_f32_16x16x32_f16(af[kc], bf[2][kc], ah2, 0, 0, 0);
            }

            // finalize: lane owns (m = quad*4+r, j) for all gates
            const int nbuf = buf ^ 1;
            #pragma unroll
            for (int r = 0; r < 4; r++) {
                const float sxr = (l == 0) ? xr[r] : ai0[r];
                const float sxz = (l == 0) ? xz[r] : ai1[r];
                const float sxn = ((l == 0) ? xn[r] : ai2[r]) + bxn;
                const float rg  = sigf(sxr + ah0[r] + bcr);
                const float zg  = sigf(sxz + ah1[r] + bcz);
                const float th  = tanh_fast(sxn + rg * (ah2[r] + bcn));
                const float hnew = fmaf(zg, vhp[r] - th, th);   // (1-z)n + z h
                vhp[r] = hnew;
                hA[nbuf][quad * 4 + r][j] = (_Float16)hnew;
                if (l < 4) hw[r * 128] = (_Float16)hnew;        // drains at chunk-end syncthreads
                if (l == 4 && t == SEQ - 1)
                    hlast[(bm0 + quad * 4 + r) * 128 + j] = hnew;
            }
            if (l < 4) hw += 2048;

            if (l == 0) {
                #pragma unroll
                for (int r = 0; r < 4; r++) { xr[r] = nr[r]; xz[r] = nz[r]; xn[r] = nn[r]; }
            }

            // in-chunk prefetch of h_prev(t+1) (covered by this chunk's acquire)
            if (l > 0 && i < CHUNK - 1) {
                const _Float16* hp = hprev + (size_t)(t + 1) * 2048 + hoff;
                #pragma unroll
                for (int kc = 0; kc < 4; kc++) ap[kc] = *(const f16x8*)(hp + kc * 32);
            }
        }

        // ---- chunk boundary: REAL barrier (drains hpub stores), then RELEASE
        __syncthreads();
        if (l < 4 && tid == 0)
            __hip_atomic_store(dstflag, t0 + CHUNK, __ATOMIC_RELEASE, __HIP_MEMORY_SCOPE_AGENT);
    }
}

// ---------------------------------------------------------------------------
// fc: out[b][o] = hlast[b][:] . fc_w[o][:] + fc_b[o]
// ---------------------------------------------------------------------------
__global__ __launch_bounds__(128) void fc_kernel(const float* __restrict__ hlast,
                                                 const float* __restrict__ fc_w,
                                                 const float* __restrict__ fc_b,
                                                 float* __restrict__ out)
{
    const int b = blockIdx.x;
    const int o = threadIdx.x;
    if (o < 96) {
        const float* h = hlast + (size_t)b * HID;
        const float* wrow = fc_w + o * HID;
        float acc = fc_b[o];
        #pragma unroll 4
        for (int k = 0; k < HID; k++) acc = fmaf(h[k], wrow[k], acc);
        out[b * 96 + o] = acc;
    }
}

// ---------------------------------------------------------------------------
extern "C" void kernel_launch(void* const* d_in, const int* in_sizes, int n_in,
                              void* d_out, int out_size, void* d_ws, size_t ws_size,
                              hipStream_t stream)
{
    const float* x         = (const float*)d_in[0]; // [64][512][512]
    const float* w_ih0     = (const float*)d_in[1]; // [384][512]
    const float* w_ih_rest = (const float*)d_in[2]; // [4][384][128]
    const float* w_hh      = (const float*)d_in[3]; // [5][384][128]
    const float* b_ih      = (const float*)d_in[4]; // [5][384]
    const float* b_hh      = (const float*)d_in[5]; // [5][384]
    const float* fc_w      = (const float*)d_in[6]; // [96][128]
    const float* fc_b      = (const float*)d_in[7]; // [96]
    float* out = (float*)d_out;                     // [64][96]

    // workspace layout:
    //   [0,64)               flags (16 ints)
    //   [64,128)             gxcnt (16 ints)       — both zeroed each launch
    //   [256, +50331648)     gxbuf fp32 [64][512][384]
    //   [.., +33554432)      hmid  f16  [4][4][512][16][128]
    //   [.., +32768)         hlast fp32 [64][128]
    int*      flags = (int*)d_ws;
    int*      gxcnt = (int*)d_ws + 16;
    float*    gxbuf = (float*)((char*)d_ws + 256);
    _Float16* hmid  = (_Float16*)((char*)d_ws + 256 + 50331648);
    float*    hlast = (float*)((char*)d_ws + 256 + 50331648 + 33554432);

    hipMemsetAsync(d_ws, 0, 256, stream);

    // 20 pipeline blocks + 1536 gemm tile blocks, one kernel
    gru_fused<<<20 + 1536, 512, 0, stream>>>(x, w_ih0, w_ih_rest, w_hh, b_ih, b_hh,
                                             gxbuf, hmid, hlast, flags, gxcnt);

    fc_kernel<<<BATCH, 128, 0, stream>>>(hlast, fc_w, fc_b, out);
}